// Round 17
// baseline (69.117 us; speedup 1.0000x reference)
//
#include <hip/hip_runtime.h>
#include <stdint.h>

#define T_TRIALS 1000
#define B_SIZE   8192
#define P_SIZE   1024
#define CHUNK    32
#define KCH      32            // 31 full chunks + 8-step tail
#define NM       31            // maps 0..30 feed the scan
#define BPB      16            // batch elements per block (>=16: 64B segments)
#define BP       17            // padded row
#define ER_DECAY 0.999f
#define ER_L2D   (-1.4434228e-3f)   // log2(0.999)
#define LOG2E_F 1.4426950408889634f
#define LN2_F   0.69314718055994531f

typedef float f32x4_t __attribute__((ext_vector_type(4)));

__device__ __forceinline__ float sp_(float x){ return __logf(1.0f + __expf(x)); }   // softplus
__device__ __forceinline__ float sg_(float x){ return 1.0f / (1.0f + __expf(-x)); } // sigmoid
__device__ __forceinline__ float clampf(float x, float lo, float hi){ return fminf(fmaxf(x, lo), hi); }

// ===========================================================================
// fused8 = R14 fused4 + select-target + phase-2 double-buffered LDS prefetch.
// Block = 512 threads = 32 chunks (k = tid>>4) x 16 b (bi = tid&15).
// ===========================================================================
__global__ __launch_bounds__(512)
void castro_fused8(const float* __restrict__ params,
                   const float* __restrict__ rewards,
                   const int*   __restrict__ choices,
                   const int*   __restrict__ pids,
                   float4*      __restrict__ out4)
{
    __shared__ float4   smap0[NM][BP];
    __shared__ float4   smap1[NM][BP];
    __shared__ float4   smap2[NM][BP];
    __shared__ float4   smap3[NM][BP];
    __shared__ float4   smap4[NM][BP];
    __shared__ uint32_t smeta[NM][BP];
    __shared__ float    pshare[BPB][10];

    const int tid = threadIdx.x;
    const int k   = tid >> 4;
    const int bi  = tid & 15;
    const int b   = blockIdx.x * BPB + bi;
    const int t0  = k * CHUNK;
    const int pid = pids[b];

    // phase-1 params (every thread computes its own 3)
    const float p3  = clampf(params[ 3 * P_SIZE + pid], -5.0f, 5.0f);
    const float p4  = clampf(params[ 4 * P_SIZE + pid], -5.0f, 5.0f);
    const float p10 = clampf(params[10 * P_SIZE + pid], -5.0f, 5.0f);
    const float alpha_er = clampf(sg_(p3), 0.01f, 0.99f);
    const float decay    = clampf(sg_(p4), 0.01f, 0.99f);
    const float gam      = sp_(p10);
    const float ngam     = -gam;

    if (tid < BPB) {
        const float q0_ = clampf(params[ 0 * P_SIZE + pid], -5.0f, 5.0f);
        const float q1_ = clampf(params[ 1 * P_SIZE + pid], -5.0f, 5.0f);
        const float q2_ = clampf(params[ 2 * P_SIZE + pid], -5.0f, 5.0f);
        const float q5_ = clampf(params[ 5 * P_SIZE + pid], -5.0f, 5.0f);
        const float q6_ = clampf(params[ 6 * P_SIZE + pid], -5.0f, 5.0f);
        const float q7_ = clampf(params[ 7 * P_SIZE + pid], -5.0f, 5.0f);
        const float q8_ = clampf(params[ 8 * P_SIZE + pid], -5.0f, 5.0f);
        const float q11 = clampf(params[11 * P_SIZE + pid], -5.0f, 5.0f);
        const float q12 = clampf(params[12 * P_SIZE + pid], -5.0f, 5.0f);
        const float beta_r = clampf(sp_(q0_), 0.01f, 20.0f);
        const float lapse  = clampf(sg_(q1_), 0.01f, 0.99f);
        const float prior  = clampf(sp_(q2_), 0.01f, 0.99f);
        const float temp   = clampf(sp_(q11) + 1e-6f, 1e-6f, 100.0f);
        pshare[tid][0] = (beta_r / temp) * LOG2E_F;
        pshare[tid][1] = 1.0f - lapse;
        pshare[tid][2] = 0.25f * lapse;
        pshare[tid][3] = prior;
        pshare[tid][4] = sp_(q7_);
        pshare[tid][5] = q8_;
        pshare[tid][6] = q5_;
        pshare[tid][7] = q6_;
        pshare[tid][8] = sp_(q12);
        pshare[tid][9] = 0.0f;
    }

    const int*   cp = choices + (size_t)t0 * B_SIZE + b;
    const float* rp = rewards + (size_t)t0 * B_SIZE + b;

    uint32_t wr[4] = {0u, 0u, 0u, 0u};

    // ---------------- phase 1: pack + per-chunk map composition ----------------
    if (k < NM) {
        float er = alpha_er * exp2f((float)t0 * ER_L2D);

        float m00=1.f,m01=0.f,m02=0.f,m03=0.f;
        float m10=0.f,m11=1.f,m12=0.f,m13=0.f;
        float m20=0.f,m21=0.f,m22=1.f,m23=0.f;
        float m30=0.f,m31=0.f,m32=0.f,m33=1.f;
        float b0=0.f,b1=0.f,b2=0.f,b3=0.f;
        int   c1=0,c2=0,c3=0;
        int   run=0, last=-1;

        int cbuf[8]; float rbuf[8];
        #pragma unroll
        for (int i = 0; i < 8; ++i) {
            cbuf[i] = cp[(size_t)i * B_SIZE];
            rbuf[i] = rp[(size_t)i * B_SIZE];
        }

        #pragma unroll
        for (int g = 0; g < 4; ++g) {
            int cc[8]; float rr[8];
            #pragma unroll
            for (int i = 0; i < 8; ++i) { cc[i]=cbuf[i]; rr[i]=rbuf[i]; }
            if (g < 3) {
                #pragma unroll
                for (int i = 0; i < 8; ++i) {
                    cbuf[i] = cp[(size_t)((g+1)*8 + i) * B_SIZE];
                    rbuf[i] = rp[(size_t)((g+1)*8 + i) * B_SIZE];
                }
            }
            uint32_t gw = 0;
            #pragma unroll
            for (int i = 0; i < 8; ++i) {
                const int  c    = cc[i];
                const bool rbit = (rr[i] > 0.5f);
                gw |= ((uint32_t)c | (rbit ? 4u : 0u)) << (4*i);

                er *= ER_DECAY;
                const float target = rbit ? 1.0f : ngam;
                const bool e0=(c==0), e1=(c==1), e2=(c==2), e3=(c==3);

                m00=e0?0.f:m00; m01=e0?0.f:m01; m02=e0?0.f:m02; m03=e0?0.f:m03; b0=e0?target:b0;
                m10=e1?0.f:m10; m11=e1?0.f:m11; m12=e1?0.f:m12; m13=e1?0.f:m13; b1=e1?target:b1;
                m20=e2?0.f:m20; m21=e2?0.f:m21; m22=e2?0.f:m22; m23=e2?0.f:m23; b2=e2?target:b2;
                m30=e3?0.f:m30; m31=e3?0.f:m31; m32=e3?0.f:m32; m33=e3?0.f:m33; b3=e3?target:b3;

                const float s0=(m00+m10)+(m20+m30);
                const float s1=(m01+m11)+(m21+m31);
                const float s2=(m02+m12)+(m22+m32);
                const float s3=(m03+m13)+(m23+m33);
                const float sb=(b0+b1)+(b2+b3);
                const float a  = decay * (1.0f - er);
                const float e4 = decay * er * 0.25f;

                m00=fmaf(e4,s0,a*m00); m01=fmaf(e4,s1,a*m01); m02=fmaf(e4,s2,a*m02); m03=fmaf(e4,s3,a*m03);
                m10=fmaf(e4,s0,a*m10); m11=fmaf(e4,s1,a*m11); m12=fmaf(e4,s2,a*m12); m13=fmaf(e4,s3,a*m13);
                m20=fmaf(e4,s0,a*m20); m21=fmaf(e4,s1,a*m21); m22=fmaf(e4,s2,a*m22); m23=fmaf(e4,s3,a*m23);
                m30=fmaf(e4,s0,a*m30); m31=fmaf(e4,s1,a*m31); m32=fmaf(e4,s2,a*m32); m33=fmaf(e4,s3,a*m33);
                b0=fmaf(e4,sb,a*b0); b1=fmaf(e4,sb,a*b1); b2=fmaf(e4,sb,a*b2); b3=fmaf(e4,sb,a*b3);

                c1 += e1; c2 += e2; c3 += e3;
                run = (c == last) ? run + 1 : 1;
                last = c;
            }
            wr[g] = gw;
        }

        smap0[k][bi] = make_float4(m00,m01,m02,m03);
        smap1[k][bi] = make_float4(m10,m11,m12,m13);
        smap2[k][bi] = make_float4(m20,m21,m22,m23);
        smap3[k][bi] = make_float4(m30,m31,m32,m33);
        smap4[k][bi] = make_float4(b0,b1,b2,b3);
        smeta[k][bi] = (uint32_t)c1 | ((uint32_t)c2<<6) | ((uint32_t)c3<<12)
                     | ((uint32_t)last<<18) | ((uint32_t)run<<20);
    } else {
        // tail chunk [992,1000): pack only
        uint32_t gw = 0;
        #pragma unroll
        for (int i = 0; i < 8; ++i) {
            const int   c = cp[(size_t)i * B_SIZE];
            const float r = rp[(size_t)i * B_SIZE];
            gw |= ((uint32_t)c | (r > 0.5f ? 4u : 0u)) << (4*i);
        }
        wr[0] = gw;
    }

    __syncthreads();

    // ---------------- phase 2: serial scan, double-buffered LDS prefetch -------
    if (tid < BPB) {
        const float prior = pshare[tid][3];
        float q0=prior, q1=prior, q2=prior, q3=prior;
        int n0=0,n1=0,n2=0,n3=0;
        int g_run=0, g_last=-1;

        // buffer A = map k2, loaded ahead
        float4 A0 = smap0[0][tid], A1 = smap1[0][tid], A2 = smap2[0][tid],
               A3 = smap3[0][tid], A4 = smap4[0][tid];
        uint32_t Am = smeta[0][tid];

        #pragma unroll
        for (int k2 = 0; k2 < KCH; ++k2) {
            if (k2 > 0) {
                const int tsls = g_run - 1;
                smap0[k2-1][tid] = make_float4(q0,q1,q2,q3);
                smap1[k2-1][tid] = make_float4(0.0f,
                                               __int_as_float(n0 | (n1<<16)),
                                               __int_as_float(n2 | (n3<<16)),
                                               __int_as_float((tsls & 0xFFFF) | (g_last<<16)));
            }
            if (k2 < NM) {
                const float4 r0=A0, r1=A1, r2=A2, r3=A3, r4=A4;
                const uint32_t m = Am;
                if (k2 + 1 < NM) {   // prefetch next map while computing this one
                    A0 = smap0[k2+1][tid]; A1 = smap1[k2+1][tid];
                    A2 = smap2[k2+1][tid]; A3 = smap3[k2+1][tid];
                    A4 = smap4[k2+1][tid]; Am = smeta[k2+1][tid];
                }
                const float nq0 = fmaf(r0.w,q3, fmaf(r0.z,q2, fmaf(r0.y,q1, fmaf(r0.x,q0, r4.x))));
                const float nq1 = fmaf(r1.w,q3, fmaf(r1.z,q2, fmaf(r1.y,q1, fmaf(r1.x,q0, r4.y))));
                const float nq2 = fmaf(r2.w,q3, fmaf(r2.z,q2, fmaf(r2.y,q1, fmaf(r2.x,q0, r4.z))));
                const float nq3 = fmaf(r3.w,q3, fmaf(r3.z,q2, fmaf(r3.y,q1, fmaf(r3.x,q0, r4.w))));
                q0=nq0; q1=nq1; q2=nq2; q3=nq3;

                const int cc1 = (int)( m        & 63u);
                const int cc2 = (int)((m >> 6 ) & 63u);
                const int cc3 = (int)((m >> 12) & 63u);
                n0 += CHUNK - cc1 - cc2 - cc3;
                n1 += cc1; n2 += cc2; n3 += cc3;
                const int last = (int)((m >> 18) & 3u);
                const int rn   = (int)((m >> 20) & 63u);
                g_run  = (rn == CHUNK && last == g_last) ? g_run + CHUNK : rn;
                g_last = last;
            }
        }
    }
    __syncthreads();

    // ---------------- phase 3: emit logits for own chunk ----------------------
    {
        const float bt2    = pshare[bi][0];
        const float ol     = pshare[bi][1];
        const float la4    = pshare[bi][2];
        const float prior  = pshare[bi][3];
        const float perv   = pshare[bi][4];
        const float sw     = pshare[bi][5];
        const float ab1    = pshare[bi][6];
        const float ab2    = pshare[bi][7];
        const float beta_p = pshare[bi][8];

        float q0,q1,q2,q3, ft;
        float f0,f1,f2,f3;
        int   old_c;
        if (k == 0) {
            q0=q1=q2=q3=prior; f0=f1=f2=f3=0.f; ft=0.f; old_c=-1;
        } else {
            const float4 sA = smap0[k-1][bi];
            const float4 sB = smap1[k-1][bi];
            q0=sA.x; q1=sA.y; q2=sA.z; q3=sA.w;
            const int u1 = __float_as_int(sB.y);
            const int u2 = __float_as_int(sB.z);
            const int u3 = __float_as_int(sB.w);
            f0 = (float)(u1 & 0xFFFF); f1 = (float)(u1 >> 16);
            f2 = (float)(u2 & 0xFFFF); f3 = (float)(u2 >> 16);
            ft = (float)(u3 & 0xFFFF);
            old_c = u3 >> 16;
        }
        float er = alpha_er * exp2f((float)t0 * ER_L2D);

        float bpl0 = beta_p * __log2f(1.0f + f0);
        float bpl1 = beta_p * __log2f(1.0f + f1);
        float bpl2 = beta_p * __log2f(1.0f + f2);
        float bpl3 = beta_p * __log2f(1.0f + f3);

        float4* op = out4 + (size_t)t0 * B_SIZE + b;
        const int ngroups = (k == NM) ? 1 : 4;

        #pragma unroll
        for (int g = 0; g < 4; ++g) {
            if (g < ngroups) {
                uint32_t word = wr[g];
                #pragma unroll
                for (int i = 0; i < 8; ++i) {
                    const int code = (int)(word & 0xFu); word >>= 4;
                    const int c    = code & 3;
                    const float target = (code & 4) ? 1.0f : ngam;
                    const bool e0=(c==0), e1=(c==1), e2=(c==2), e3=(c==3);

                    q0 = e0 ? target : q0;
                    q1 = e1 ? target : q1;
                    q2 = e2 ? target : q2;
                    q3 = e3 ? target : q3;

                    const bool same = (c == old_c);
                    ft = same ? ft + 1.0f : 0.0f;
                    er *= ER_DECAY;

                    const float fsel = e0 ? f0 : (e1 ? f1 : (e2 ? f2 : f3));
                    const float bplc = beta_p * __log2f(fsel + 2.0f);
                    f0 += e0 ? 1.0f : 0.0f;
                    f1 += e1 ? 1.0f : 0.0f;
                    f2 += e2 ? 1.0f : 0.0f;
                    f3 += e3 ? 1.0f : 0.0f;
                    bpl0 = e0 ? bplc : bpl0;
                    bpl1 = e1 ? bplc : bpl1;
                    bpl2 = e2 ? bplc : bpl2;
                    bpl3 = e3 ? bplc : bpl3;

                    const float qm = 0.25f * ((q0+q1)+(q2+q3));
                    q0 = decay * fmaf(er, qm - q0, q0);
                    q1 = decay * fmaf(er, qm - q1, q1);
                    q2 = decay * fmaf(er, qm - q2, q2);
                    q3 = decay * fmaf(er, qm - q3, q3);

                    const float s0 = fmaf(bt2, q0, bpl0);
                    const float s1 = fmaf(bt2, q1, bpl1);
                    const float s2 = fmaf(bt2, q2, bpl2);
                    const float s3 = fmaf(bt2, q3, bpl3);

                    const float m  = fmaxf(fmaxf(s0, s1), fmaxf(s2, s3));
                    const float x0 = exp2f(s0 - m);
                    const float x1 = exp2f(s1 - m);
                    const float x2 = exp2f(s2 - m);
                    const float x3 = exp2f(s3 - m);
                    const float inv = __builtin_amdgcn_rcpf((x0+x1)+(x2+x3));
                    const float sc  = ol * inv;

                    const float L0 = __log2f(fmaf(sc, x0, la4));
                    const float L1 = __log2f(fmaf(sc, x1, la4));
                    const float L2 = __log2f(fmaf(sc, x2, la4));
                    const float L3 = __log2f(fmaf(sc, x3, la4));

                    const float bonus = fmaf(LN2_F, __log2f(ft + 1.0f), same ? perv : sw);

                    float a0 = (e0 ? bonus : 0.0f) + ((old_c == 0) ? ab1 : 0.0f);
                    float a1 = (e1 ? bonus : 0.0f) + ((old_c == 1) ? ab1 : 0.0f);
                    float a2 = (e2 ? bonus : 0.0f) + ((old_c == 2) ? ab1 : 0.0f);
                    float a3 = (e3 ? bonus : 0.0f) + ((old_c == 3) ? ab1 : 0.0f);
                    const int c2 = (c + 2) & 3;
                    a0 += (c2 == 0) ? ab2 : 0.0f;
                    a1 += (c2 == 1) ? ab2 : 0.0f;
                    a2 += (c2 == 2) ? ab2 : 0.0f;
                    a3 += (c2 == 3) ? ab2 : 0.0f;

                    f32x4_t v = { fmaf(LN2_F, L0, a0), fmaf(LN2_F, L1, a1),
                                  fmaf(LN2_F, L2, a2), fmaf(LN2_F, L3, a3) };
                    __builtin_nontemporal_store(v,
                        reinterpret_cast<f32x4_t*>(op + (size_t)(g*8 + i) * B_SIZE));
                    old_c = c;
                }
            }
        }
    }
}

extern "C" void kernel_launch(void* const* d_in, const int* in_sizes, int n_in,
                              void* d_out, int out_size, void* d_ws, size_t ws_size,
                              hipStream_t stream)
{
    const float* params  = (const float*)d_in[0];
    const float* rewards = (const float*)d_in[1];
    const int*   choices = (const int*)  d_in[2];
    const int*   pids    = (const int*)  d_in[3];

    hipLaunchKernelGGL(castro_fused8, dim3(B_SIZE/BPB), dim3(512), 0, stream,
                       params, rewards, choices, pids, (float4*)d_out);
}

// Round 18
// 62.239 us; speedup vs baseline: 1.1105x; 1.1105x over previous
//
#include <hip/hip_runtime.h>
#include <stdint.h>

#define T_TRIALS 1000
#define B_SIZE   8192
#define P_SIZE   1024
#define CHUNK    32
#define KCH      32            // 31 full chunks + 8-step tail
#define NM       31            // maps 0..30 feed the scan
#define BPB      16            // batch elements per block (>=16: 64B segments!)
#define BP       17            // padded row (bank spread)
#define ER_DECAY 0.999f
#define ER_L2D   (-1.4434228e-3f)   // log2(0.999)
#define LOG2E_F 1.4426950408889634f
#define LN2_F   0.69314718055994531f

typedef float f32x4_t __attribute__((ext_vector_type(4)));

__device__ __forceinline__ float sp_(float x){ return __logf(1.0f + __expf(x)); }   // softplus
__device__ __forceinline__ float sg_(float x){ return 1.0f / (1.0f + __expf(-x)); } // sigmoid
__device__ __forceinline__ float clampf(float x, float lo, float hi){ return fminf(fmaxf(x, lo), hi); }

// ===========================================================================
// Single fused kernel, b-major lanes (R12 geometry), LDS-squeezed. (R14 best)
// Block = 512 threads = 32 chunks (k = tid>>4) x 16 b (bi = tid&15).
// Phase 1: compose 32-step affine q-map -> LDS; pack (c,r) into 4 VGPRs.
// Phase 2: threads 0..15 serially scan the 31 maps; checkpoints overlay
//          into consumed map rows (smap0/1[k2-1]).
// Phase 3: every thread emits its chunk's logits from registers.
// ===========================================================================
__global__ __launch_bounds__(512)
void castro_fused4(const float* __restrict__ params,
                   const float* __restrict__ rewards,
                   const int*   __restrict__ choices,
                   const int*   __restrict__ pids,
                   float4*      __restrict__ out4)
{
    __shared__ float4   smap0[NM][BP];
    __shared__ float4   smap1[NM][BP];
    __shared__ float4   smap2[NM][BP];
    __shared__ float4   smap3[NM][BP];
    __shared__ float4   smap4[NM][BP];
    __shared__ uint32_t smeta[NM][BP];
    __shared__ float    pshare[BPB][10];

    const int tid = threadIdx.x;
    const int k   = tid >> 4;
    const int bi  = tid & 15;
    const int b   = blockIdx.x * BPB + bi;
    const int t0  = k * CHUNK;
    const int pid = pids[b];

    // phase-1 params (every thread computes its own 3)
    const float p3  = clampf(params[ 3 * P_SIZE + pid], -5.0f, 5.0f);
    const float p4  = clampf(params[ 4 * P_SIZE + pid], -5.0f, 5.0f);
    const float p10 = clampf(params[10 * P_SIZE + pid], -5.0f, 5.0f);
    const float alpha_er = clampf(sg_(p3), 0.01f, 0.99f);
    const float decay    = clampf(sg_(p4), 0.01f, 0.99f);
    const float gam      = sp_(p10);
    const float gp1      = 1.0f + gam;

    // emit-only derived params: computed once per b by threads 0..15
    if (tid < BPB) {
        const float q0_ = clampf(params[ 0 * P_SIZE + pid], -5.0f, 5.0f);
        const float q1_ = clampf(params[ 1 * P_SIZE + pid], -5.0f, 5.0f);
        const float q2_ = clampf(params[ 2 * P_SIZE + pid], -5.0f, 5.0f);
        const float q5_ = clampf(params[ 5 * P_SIZE + pid], -5.0f, 5.0f);
        const float q6_ = clampf(params[ 6 * P_SIZE + pid], -5.0f, 5.0f);
        const float q7_ = clampf(params[ 7 * P_SIZE + pid], -5.0f, 5.0f);
        const float q8_ = clampf(params[ 8 * P_SIZE + pid], -5.0f, 5.0f);
        const float q11 = clampf(params[11 * P_SIZE + pid], -5.0f, 5.0f);
        const float q12 = clampf(params[12 * P_SIZE + pid], -5.0f, 5.0f);
        const float beta_r = clampf(sp_(q0_), 0.01f, 20.0f);
        const float lapse  = clampf(sg_(q1_), 0.01f, 0.99f);
        const float prior  = clampf(sp_(q2_), 0.01f, 0.99f);
        const float temp   = clampf(sp_(q11) + 1e-6f, 1e-6f, 100.0f);
        pshare[tid][0] = (beta_r / temp) * LOG2E_F;
        pshare[tid][1] = 1.0f - lapse;
        pshare[tid][2] = 0.25f * lapse;
        pshare[tid][3] = prior;
        pshare[tid][4] = sp_(q7_);
        pshare[tid][5] = q8_;
        pshare[tid][6] = q5_;
        pshare[tid][7] = q6_;
        pshare[tid][8] = sp_(q12);
        pshare[tid][9] = 0.0f;
    }

    const int*   cp = choices + (size_t)t0 * B_SIZE + b;
    const float* rp = rewards + (size_t)t0 * B_SIZE + b;

    uint32_t wr[4] = {0u, 0u, 0u, 0u};

    // ---------------- phase 1: pack + per-chunk map composition ----------------
    if (k < NM) {
        float er = alpha_er * exp2f((float)t0 * ER_L2D);

        float m00=1.f,m01=0.f,m02=0.f,m03=0.f;
        float m10=0.f,m11=1.f,m12=0.f,m13=0.f;
        float m20=0.f,m21=0.f,m22=1.f,m23=0.f;
        float m30=0.f,m31=0.f,m32=0.f,m33=1.f;
        float b0=0.f,b1=0.f,b2=0.f,b3=0.f;
        int   c1=0,c2=0,c3=0;
        int   run=0, last=-1;

        int cbuf[8]; float rbuf[8];
        #pragma unroll
        for (int i = 0; i < 8; ++i) {
            cbuf[i] = cp[(size_t)i * B_SIZE];
            rbuf[i] = rp[(size_t)i * B_SIZE];
        }

        #pragma unroll
        for (int g = 0; g < 4; ++g) {
            int cc[8]; float rr[8];
            #pragma unroll
            for (int i = 0; i < 8; ++i) { cc[i]=cbuf[i]; rr[i]=rbuf[i]; }
            if (g < 3) {
                #pragma unroll
                for (int i = 0; i < 8; ++i) {
                    cbuf[i] = cp[(size_t)((g+1)*8 + i) * B_SIZE];
                    rbuf[i] = rp[(size_t)((g+1)*8 + i) * B_SIZE];
                }
            }
            uint32_t gw = 0;
            #pragma unroll
            for (int i = 0; i < 8; ++i) {
                const int   c = cc[i];
                const float r = rr[i];
                gw |= ((uint32_t)c | (r > 0.5f ? 4u : 0u)) << (4*i);

                er *= ER_DECAY;
                const float target = fmaf(r, gp1, -gam);
                const bool e0=(c==0), e1=(c==1), e2=(c==2), e3=(c==3);

                m00=e0?0.f:m00; m01=e0?0.f:m01; m02=e0?0.f:m02; m03=e0?0.f:m03; b0=e0?target:b0;
                m10=e1?0.f:m10; m11=e1?0.f:m11; m12=e1?0.f:m12; m13=e1?0.f:m13; b1=e1?target:b1;
                m20=e2?0.f:m20; m21=e2?0.f:m21; m22=e2?0.f:m22; m23=e2?0.f:m23; b2=e2?target:b2;
                m30=e3?0.f:m30; m31=e3?0.f:m31; m32=e3?0.f:m32; m33=e3?0.f:m33; b3=e3?target:b3;

                const float s0=(m00+m10)+(m20+m30);
                const float s1=(m01+m11)+(m21+m31);
                const float s2=(m02+m12)+(m22+m32);
                const float s3=(m03+m13)+(m23+m33);
                const float sb=(b0+b1)+(b2+b3);
                const float a  = decay * (1.0f - er);
                const float e4 = decay * er * 0.25f;

                m00=fmaf(e4,s0,a*m00); m01=fmaf(e4,s1,a*m01); m02=fmaf(e4,s2,a*m02); m03=fmaf(e4,s3,a*m03);
                m10=fmaf(e4,s0,a*m10); m11=fmaf(e4,s1,a*m11); m12=fmaf(e4,s2,a*m12); m13=fmaf(e4,s3,a*m13);
                m20=fmaf(e4,s0,a*m20); m21=fmaf(e4,s1,a*m21); m22=fmaf(e4,s2,a*m22); m23=fmaf(e4,s3,a*m23);
                m30=fmaf(e4,s0,a*m30); m31=fmaf(e4,s1,a*m31); m32=fmaf(e4,s2,a*m32); m33=fmaf(e4,s3,a*m33);
                b0=fmaf(e4,sb,a*b0); b1=fmaf(e4,sb,a*b1); b2=fmaf(e4,sb,a*b2); b3=fmaf(e4,sb,a*b3);

                c1 += e1; c2 += e2; c3 += e3;
                run = (c == last) ? run + 1 : 1;
                last = c;
            }
            wr[g] = gw;
        }

        smap0[k][bi] = make_float4(m00,m01,m02,m03);
        smap1[k][bi] = make_float4(m10,m11,m12,m13);
        smap2[k][bi] = make_float4(m20,m21,m22,m23);
        smap3[k][bi] = make_float4(m30,m31,m32,m33);
        smap4[k][bi] = make_float4(b0,b1,b2,b3);
        smeta[k][bi] = (uint32_t)c1 | ((uint32_t)c2<<6) | ((uint32_t)c3<<12)
                     | ((uint32_t)last<<18) | ((uint32_t)run<<20);
    } else {
        // tail chunk [992,1000): pack only (its map is never consumed)
        uint32_t gw = 0;
        #pragma unroll
        for (int i = 0; i < 8; ++i) {
            const int   c = cp[(size_t)i * B_SIZE];
            const float r = rp[(size_t)i * B_SIZE];
            gw |= ((uint32_t)c | (r > 0.5f ? 4u : 0u)) << (4*i);
        }
        wr[0] = gw;
    }

    __syncthreads();

    // ---------------- phase 2: serial scan (threads 0..15, one per b) ----------
    // checkpoint entering chunk k2 overlays into consumed rows smap0/1[k2-1]
    if (tid < BPB) {
        const float prior = pshare[tid][3];
        float q0=prior, q1=prior, q2=prior, q3=prior;
        int n0=0,n1=0,n2=0,n3=0;
        int g_run=0, g_last=-1;

        for (int k2 = 0; k2 < KCH; ++k2) {
            if (k2 > 0) {
                const int tsls = g_run - 1;
                smap0[k2-1][tid] = make_float4(q0,q1,q2,q3);
                smap1[k2-1][tid] = make_float4(0.0f,
                                               __int_as_float(n0 | (n1<<16)),
                                               __int_as_float(n2 | (n3<<16)),
                                               __int_as_float((tsls & 0xFFFF) | (g_last<<16)));
            }
            if (k2 < NM) {
                const float4 r0 = smap0[k2][tid];
                const float4 r1 = smap1[k2][tid];
                const float4 r2 = smap2[k2][tid];
                const float4 r3 = smap3[k2][tid];
                const float4 r4 = smap4[k2][tid];
                const uint32_t m = smeta[k2][tid];
                const float nq0 = fmaf(r0.w,q3, fmaf(r0.z,q2, fmaf(r0.y,q1, fmaf(r0.x,q0, r4.x))));
                const float nq1 = fmaf(r1.w,q3, fmaf(r1.z,q2, fmaf(r1.y,q1, fmaf(r1.x,q0, r4.y))));
                const float nq2 = fmaf(r2.w,q3, fmaf(r2.z,q2, fmaf(r2.y,q1, fmaf(r2.x,q0, r4.z))));
                const float nq3 = fmaf(r3.w,q3, fmaf(r3.z,q2, fmaf(r3.y,q1, fmaf(r3.x,q0, r4.w))));
                q0=nq0; q1=nq1; q2=nq2; q3=nq3;

                const int cc1 = (int)( m        & 63u);
                const int cc2 = (int)((m >> 6 ) & 63u);
                const int cc3 = (int)((m >> 12) & 63u);
                n0 += CHUNK - cc1 - cc2 - cc3;
                n1 += cc1; n2 += cc2; n3 += cc3;
                const int last = (int)((m >> 18) & 3u);
                const int rn   = (int)((m >> 20) & 63u);
                g_run  = (rn == CHUNK && last == g_last) ? g_run + CHUNK : rn;
                g_last = last;
            }
        }
    }
    __syncthreads();

    // ---------------- phase 3: emit logits for own chunk ----------------------
    {
        const float bt2    = pshare[bi][0];
        const float ol     = pshare[bi][1];
        const float la4    = pshare[bi][2];
        const float prior  = pshare[bi][3];
        const float perv   = pshare[bi][4];
        const float sw     = pshare[bi][5];
        const float ab1    = pshare[bi][6];
        const float ab2    = pshare[bi][7];
        const float beta_p = pshare[bi][8];

        float q0,q1,q2,q3, ft;
        float f0,f1,f2,f3;
        int   old_c;
        if (k == 0) {
            q0=q1=q2=q3=prior; f0=f1=f2=f3=0.f; ft=0.f; old_c=-1;
        } else {
            const float4 sA = smap0[k-1][bi];
            const float4 sB = smap1[k-1][bi];
            q0=sA.x; q1=sA.y; q2=sA.z; q3=sA.w;
            const int u1 = __float_as_int(sB.y);
            const int u2 = __float_as_int(sB.z);
            const int u3 = __float_as_int(sB.w);
            f0 = (float)(u1 & 0xFFFF); f1 = (float)(u1 >> 16);
            f2 = (float)(u2 & 0xFFFF); f3 = (float)(u2 >> 16);
            ft = (float)(u3 & 0xFFFF);
            old_c = u3 >> 16;          // arithmetic shift (always 0..3 here)
        }
        float er = alpha_er * exp2f((float)t0 * ER_L2D);

        float bpl0 = beta_p * __log2f(1.0f + f0);
        float bpl1 = beta_p * __log2f(1.0f + f1);
        float bpl2 = beta_p * __log2f(1.0f + f2);
        float bpl3 = beta_p * __log2f(1.0f + f3);

        float4* op = out4 + (size_t)t0 * B_SIZE + b;
        const int ngroups = (k == NM) ? 1 : 4;

        #pragma unroll
        for (int g = 0; g < 4; ++g) {
            if (g < ngroups) {
                uint32_t word = wr[g];
                #pragma unroll
                for (int i = 0; i < 8; ++i) {
                    const int   code = (int)(word & 0xFu); word >>= 4;
                    const int   c    = code & 3;
                    const float r    = (float)((code >> 2) & 1);

                    const float target = fmaf(r, gp1, -gam);
                    const bool e0=(c==0), e1=(c==1), e2=(c==2), e3=(c==3);
                    q0 = e0 ? target : q0;
                    q1 = e1 ? target : q1;
                    q2 = e2 ? target : q2;
                    q3 = e3 ? target : q3;

                    const bool same = (c == old_c);
                    ft = same ? ft + 1.0f : 0.0f;
                    er *= ER_DECAY;

                    const float fsel = e0 ? f0 : (e1 ? f1 : (e2 ? f2 : f3));
                    const float bplc = beta_p * __log2f(fsel + 2.0f);
                    f0 += e0 ? 1.0f : 0.0f;
                    f1 += e1 ? 1.0f : 0.0f;
                    f2 += e2 ? 1.0f : 0.0f;
                    f3 += e3 ? 1.0f : 0.0f;
                    bpl0 = e0 ? bplc : bpl0;
                    bpl1 = e1 ? bplc : bpl1;
                    bpl2 = e2 ? bplc : bpl2;
                    bpl3 = e3 ? bplc : bpl3;

                    const float qm = 0.25f * ((q0+q1)+(q2+q3));
                    q0 = decay * fmaf(er, qm - q0, q0);
                    q1 = decay * fmaf(er, qm - q1, q1);
                    q2 = decay * fmaf(er, qm - q2, q2);
                    q3 = decay * fmaf(er, qm - q3, q3);

                    const float s0 = fmaf(bt2, q0, bpl0);
                    const float s1 = fmaf(bt2, q1, bpl1);
                    const float s2 = fmaf(bt2, q2, bpl2);
                    const float s3 = fmaf(bt2, q3, bpl3);

                    const float m  = fmaxf(fmaxf(s0, s1), fmaxf(s2, s3));
                    const float x0 = exp2f(s0 - m);
                    const float x1 = exp2f(s1 - m);
                    const float x2 = exp2f(s2 - m);
                    const float x3 = exp2f(s3 - m);
                    const float inv = __builtin_amdgcn_rcpf((x0+x1)+(x2+x3));
                    const float sc  = ol * inv;

                    const float L0 = __log2f(fmaf(sc, x0, la4));
                    const float L1 = __log2f(fmaf(sc, x1, la4));
                    const float L2 = __log2f(fmaf(sc, x2, la4));
                    const float L3 = __log2f(fmaf(sc, x3, la4));

                    const float bonus = fmaf(LN2_F, __log2f(ft + 1.0f), same ? perv : sw);

                    float a0 = (e0 ? bonus : 0.0f) + ((old_c == 0) ? ab1 : 0.0f);
                    float a1 = (e1 ? bonus : 0.0f) + ((old_c == 1) ? ab1 : 0.0f);
                    float a2 = (e2 ? bonus : 0.0f) + ((old_c == 2) ? ab1 : 0.0f);
                    float a3 = (e3 ? bonus : 0.0f) + ((old_c == 3) ? ab1 : 0.0f);
                    const int c2 = (c + 2) & 3;
                    a0 += (c2 == 0) ? ab2 : 0.0f;
                    a1 += (c2 == 1) ? ab2 : 0.0f;
                    a2 += (c2 == 2) ? ab2 : 0.0f;
                    a3 += (c2 == 3) ? ab2 : 0.0f;

                    f32x4_t v = { fmaf(LN2_F, L0, a0), fmaf(LN2_F, L1, a1),
                                  fmaf(LN2_F, L2, a2), fmaf(LN2_F, L3, a3) };
                    __builtin_nontemporal_store(v,
                        reinterpret_cast<f32x4_t*>(op + (size_t)(g*8 + i) * B_SIZE));
                    old_c = c;
                }
            }
        }
    }
}

extern "C" void kernel_launch(void* const* d_in, const int* in_sizes, int n_in,
                              void* d_out, int out_size, void* d_ws, size_t ws_size,
                              hipStream_t stream)
{
    const float* params  = (const float*)d_in[0];
    const float* rewards = (const float*)d_in[1];
    const int*   choices = (const int*)  d_in[2];
    const int*   pids    = (const int*)  d_in[3];

    hipLaunchKernelGGL(castro_fused4, dim3(B_SIZE/BPB), dim3(512), 0, stream,
                       params, rewards, choices, pids, (float4*)d_out);
}